// Round 14
// baseline (120.105 us; speedup 1.0000x reference)
//
#include <hip/hip_runtime.h>

// N=64 nodes, H=64, M=32, B=16384.
// R11 result: 4-stream ILP gained only 1.7us and VGPR_Count=100 -> the
// pre-RA scheduler RE-SERIALIZED the streams to minimize register pressure
// (4 concurrent streams need ~150+ regs). Wall ~6400cyc/chunk-pair vs
// ~1850cyc of issue = ~70% dependency stall at phase boundaries of the
// serialized schedule. Occupancy is pinned at 2 waves/SIMD regardless
// (R7: unified VGPR+AGPR file), so the 256-reg budget is free.
// R12: pin a PHASE-BATCHED schedule with sched_group_barrier:
// [all 64 A-MFMAs][all packs][32 B-MFMAs][packs][32 C-MFMAs][tail].
// Batched issue hides MFMA/pack latency under issue throughput itself.

typedef short bf16x8 __attribute__((ext_vector_type(8)));
typedef float f32x4  __attribute__((ext_vector_type(4)));
typedef unsigned int u32x4 __attribute__((ext_vector_type(4)));

// LLVM SchedGroupMask: VALU=0x2, MFMA=0x8, VMEM_READ=0x20, DS_READ=0x100
#define SGB(mask, n) __builtin_amdgcn_sched_group_barrier((mask), (n), 0)

__device__ __forceinline__ unsigned int pack2(float a, float b) {
    // f32x2 -> packed bf16x2 in ONE VALU op (RTNE); a -> low16, b -> high16
    unsigned int r;
    asm("v_cvt_pk_bf16_f32 %0, %1, %2" : "=v"(r) : "v"(a), "v"(b));
    return r;
}

__device__ __forceinline__ f32x4 mfma16(bf16x8 a, bf16x8 b, f32x4 c) {
    return __builtin_amdgcn_mfma_f32_16x16x32_bf16(a, b, c, 0, 0, 0);
}

// pack two relu'd f32x4 D-blocks into one bf16x8 B-operand fragment
__device__ __forceinline__ bf16x8 pack_frag(f32x4 lo, f32x4 hi) {
    union { u32x4 u; bf16x8 v; } r;
    r.u[0] = pack2(fmaxf(lo[0], 0.f), fmaxf(lo[1], 0.f));
    r.u[1] = pack2(fmaxf(lo[2], 0.f), fmaxf(lo[3], 0.f));
    r.u[2] = pack2(fmaxf(hi[0], 0.f), fmaxf(hi[1], 0.f));
    r.u[3] = pack2(fmaxf(hi[2], 0.f), fmaxf(hi[3], 0.f));
    return r.v;
}

// convert 2x f32x4 (possibly non-adjacent) into a bf16x8 A-fragment
__device__ __forceinline__ bf16x8 cvt_frag2(const float* __restrict__ plo,
                                            const float* __restrict__ phi) {
    f32x4 f0 = *(const f32x4*)plo;
    f32x4 f1 = *(const f32x4*)phi;
    union { u32x4 u; bf16x8 v; } r;
    r.u[0] = pack2(f0[0], f0[1]);
    r.u[1] = pack2(f0[2], f0[3]);
    r.u[2] = pack2(f1[0], f1[1]);
    r.u[3] = pack2(f1[2], f1[3]);
    return r.v;
}

__device__ __forceinline__ bf16x8 cvt_frag2_m(const float* __restrict__ plo,
                                              const float* __restrict__ phi,
                                              const unsigned int* M) {
    f32x4 f0 = *(const f32x4*)plo;
    f32x4 f1 = *(const f32x4*)phi;
    union { u32x4 u; bf16x8 v; } r;
    r.u[0] = pack2(f0[0], f0[1]) & M[0];
    r.u[1] = pack2(f0[2], f0[3]) & M[1];
    r.u[2] = pack2(f1[0], f1[1]) & M[2];
    r.u[3] = pack2(f1[2], f1[3]) & M[3];
    return r.v;
}

__global__ __launch_bounds__(256) void prep_x(const float* __restrict__ x,
                                              unsigned short* __restrict__ xb) {
    int j = (blockIdx.x * 256 + threadIdx.x) * 8;
    f32x4 a = *(const f32x4*)&x[j];
    f32x4 b = *(const f32x4*)&x[j + 4];
    u32x4 r = { pack2(a[0], a[1]), pack2(a[2], a[3]), pack2(b[0], b[1]), pack2(b[2], b[3]) };
    *(u32x4*)&xb[j] = r;
}

__global__ __launch_bounds__(256, 2) void main_kernel(
    const float* __restrict__ x,
    const float* __restrict__ W1a, const float* __restrict__ W1b,
    const float* __restrict__ W2a, const float* __restrict__ W2b,
    const float* __restrict__ W3a, const float* __restrict__ b3a,
    const float* __restrict__ W3b, const float* __restrict__ b3b,
    const unsigned short* __restrict__ xb,
    float* __restrict__ out)
{
    const int i    = blockIdx.x & 63;   // same-i blocks 64-strided -> same XCD (weight L2 locality)
    const int bg   = blockIdx.x >> 6;   // 0..7
    const int tid  = threadIdx.x;
    const int w    = tid >> 6;
    const int lane = tid & 63;
    const int q    = lane >> 4;
    const int c0   = lane & 15;

    // Layout: [0, 32768)B frag region (32 frags x 1024B);
    //         [32768, 33536)B s_vec region (3 x 256B);
    //         pad to 56320B -> 2 blocks/CU (256-reg budget).
    __shared__ short lds[28160];

    // masks zeroing weight input-column i of W1a/W2a (== masking x column i)
    unsigned int M[2][4];
    {
        const unsigned int halfmask = (i & 1) ? 0x0000FFFFu : 0xFFFF0000u;
        const int dz = (i >> 1) & 3;
        #pragma unroll
        for (int s = 0; s < 2; ++s) {
            bool hit = ((i >> 3) == s * 4 + q);
            #pragma unroll
            for (int d = 0; d < 4; ++d)
                M[s][d] = (hit && d == dz) ? halfmask : 0xFFFFFFFFu;
        }
    }

    // ---- prologue: build all fragments in LDS (each wave owns 8 frag slots) ----
    if (w == 0) {
        const float* p1 = W1a + (i << 12);
        #pragma unroll
        for (int j = 0; j < 8; ++j) {
            int t = j >> 1, s = j & 1;
            int off = (((t << 4) + c0) << 6) + (s << 5) + (q << 3);
            bf16x8 fr = cvt_frag2_m(p1 + off, p1 + off + 4, M[s]);
            *(bf16x8*)&lds[j * 512 + lane * 8] = fr;
        }
    } else if (w == 1) {
        const float* p2 = W2a + (i << 12);
        #pragma unroll
        for (int j = 0; j < 8; ++j) {
            int t = j >> 1, s = j & 1;
            int off = (((t << 4) + c0) << 6) + (s << 5) + (q << 3);
            bf16x8 fr = cvt_frag2_m(p2 + off, p2 + off + 4, M[s]);
            *(bf16x8*)&lds[(8 + j) * 512 + lane * 8] = fr;
        }
    } else if (w == 2) {
        const float* p3 = W3a + (i << 13);
        #pragma unroll
        for (int j = 0; j < 8; ++j) {
            int t = j >> 1, s = j & 1;
            int base = (((t << 4) + c0) << 7) + (s << 5) + (q << 2);
            bf16x8 fr = cvt_frag2(p3 + base, p3 + base + 16);
            *(bf16x8*)&lds[(16 + j) * 512 + lane * 8] = fr;
        }
    } else {
        const float* pb1 = W1b + (i << 11);
        const float* pb2 = W2b + (i << 11);
        #pragma unroll
        for (int j = 0; j < 4; ++j) {
            int t = j >> 1, s = j & 1;
            int base = (((t << 4) + c0) << 6) + (s << 5) + (q << 2);
            bf16x8 fr1 = cvt_frag2(pb1 + base, pb1 + base + 16);
            bf16x8 fr2 = cvt_frag2(pb2 + base, pb2 + base + 16);
            *(bf16x8*)&lds[(24 + j) * 512 + lane * 8] = fr1;
            *(bf16x8*)&lds[(28 + j) * 512 + lane * 8] = fr2;
        }
    }
    if (tid < 64) {
        float* sv = (float*)&lds[16384];
        int tt = tid >> 4, qq = (tid >> 2) & 3, rr = tid & 3;
        sv[0 * 64 + tt * 16 + qq * 4 + rr] = b3a[(i << 6) + tid];
        sv[2 * 64 + tt * 16 + qq * 4 + rr] = W3b[(i << 6) + tid];
        sv[1 * 64 + tt * 16 + qq * 4 + rr] = W3a[(i << 13) + (tid << 7) + 64 + i];
    }
    const float bb = b3b[i];
    __syncthreads();

    const float* sv = (const float*)&lds[16384];

    const int wbase = (((bg << 2) + w) << 9);  // 512 rows per wave, 8 chunks of 64

    for (int k = 0; k < 8; ++k) {
        const int cb = wbase + (k << 6) + c0;

        // ---- load this chunk's 4 subtiles of x ----
        bf16x8 XB0[4], XB1[4]; float xd[4];
        #pragma unroll
        for (int r = 0; r < 4; ++r) {
            int rw = cb + (r << 4);
            XB0[r] = *(const bf16x8*)&xb[(rw << 6) + (q << 3)];
            XB1[r] = *(const bf16x8*)&xb[(rw << 6) + 32 + (q << 3)];
            xd[r]  = x[(rw << 6) + i];
        }
        SGB(0x20, 12);    // 12 global loads issue first

        // ---- phase A: x -> Ha (W1a), x -> Hb (W2a); 4 independent streams ----
        f32x4 a1[4][4], a2[4][4];
        #pragma unroll
        for (int t = 0; t < 4; ++t) {
            bf16x8 f10 = *(const bf16x8*)&lds[(t * 2 + 0) * 512 + lane * 8];
            bf16x8 f11 = *(const bf16x8*)&lds[(t * 2 + 1) * 512 + lane * 8];
            bf16x8 f20 = *(const bf16x8*)&lds[(8 + t * 2 + 0) * 512 + lane * 8];
            bf16x8 f21 = *(const bf16x8*)&lds[(8 + t * 2 + 1) * 512 + lane * 8];
            #pragma unroll
            for (int r = 0; r < 4; ++r) {
                f32x4 z = {0.f, 0.f, 0.f, 0.f};
                a1[t][r] = mfma16(f11, XB1[r], mfma16(f10, XB0[r], z));
                a2[t][r] = mfma16(f21, XB1[r], mfma16(f20, XB0[r], z));
            }
        }
        SGB(0x100, 16);   // 16 ds_read (A frags)
        SGB(0x8, 64);     // then ALL 64 phase-A MFMAs back-to-back

        bf16x8 HB0[4], HB1[4], GB0[4], GB1[4];
        #pragma unroll
        for (int r = 0; r < 4; ++r) {
            HB0[r] = pack_frag(a1[0][r], a1[1][r]);
            HB1[r] = pack_frag(a1[2][r], a1[3][r]);
            GB0[r] = pack_frag(a2[0][r], a2[1][r]);
            GB1[r] = pack_frag(a2[2][r], a2[3][r]);
        }
        SGB(0x2, 192);    // all A-pack VALU (16 pack_frag x 12 ops)

        // ---- phase B: Ha -> r1 (W1b), Hb -> r2 (W2b) ----
        f32x4 b1[2][4], b2[2][4];
        #pragma unroll
        for (int t = 0; t < 2; ++t) {
            bf16x8 g10 = *(const bf16x8*)&lds[(24 + t * 2 + 0) * 512 + lane * 8];
            bf16x8 g11 = *(const bf16x8*)&lds[(24 + t * 2 + 1) * 512 + lane * 8];
            bf16x8 g20 = *(const bf16x8*)&lds[(28 + t * 2 + 0) * 512 + lane * 8];
            bf16x8 g21 = *(const bf16x8*)&lds[(28 + t * 2 + 1) * 512 + lane * 8];
            #pragma unroll
            for (int r = 0; r < 4; ++r) {
                f32x4 z = {0.f, 0.f, 0.f, 0.f};
                b1[t][r] = mfma16(g11, HB1[r], mfma16(g10, HB0[r], z));
                b2[t][r] = mfma16(g21, GB1[r], mfma16(g20, GB0[r], z));
            }
        }
        SGB(0x100, 8);    // 8 ds_read (B frags)
        SGB(0x8, 32);     // all 32 phase-B MFMAs

        bf16x8 RB0[4], RB1[4];
        #pragma unroll
        for (int r = 0; r < 4; ++r) {
            RB0[r] = pack_frag(b1[0][r], b1[1][r]);   // r1 -> A3 s=0 slots
            RB1[r] = pack_frag(b2[0][r], b2[1][r]);   // r2 -> A3 s=1 slots
        }
        SGB(0x2, 96);     // all B-pack VALU

        // ---- phase C: h = W3a'*[r1;r2] + xd*w3x + b3a; out = relu(dot(relu(h), w3b) + bb) ----
        float p[4] = {0.f, 0.f, 0.f, 0.f};
        #pragma unroll
        for (int t = 0; t < 4; ++t) {
            bf16x8 h0 = *(const bf16x8*)&lds[(16 + t * 2 + 0) * 512 + lane * 8];
            bf16x8 h1 = *(const bf16x8*)&lds[(16 + t * 2 + 1) * 512 + lane * 8];
            f32x4 bv = *(const f32x4*)&sv[0 * 64 + t * 16 + q * 4];
            f32x4 xv = *(const f32x4*)&sv[1 * 64 + t * 16 + q * 4];
            f32x4 wv = *(const f32x4*)&sv[2 * 64 + t * 16 + q * 4];
            #pragma unroll
            for (int r = 0; r < 4; ++r) {
                f32x4 acc;
                #pragma unroll
                for (int e = 0; e < 4; ++e) acc[e] = fmaf(xd[r], xv[e], bv[e]);
                acc = mfma16(h0, RB0[r], acc);
                acc = mfma16(h1, RB1[r], acc);
                #pragma unroll
                for (int e = 0; e < 4; ++e) p[r] = fmaf(fmaxf(acc[e], 0.f), wv[e], p[r]);
            }
        }
        SGB(0x100, 20);   // C frag + s_vec ds_reads
        SGB(0x2, 64);     // pre-bias fmas
        SGB(0x8, 32);     // all 32 phase-C MFMAs
        SGB(0x2, 128);    // relu+dot tail

        #pragma unroll
        for (int r = 0; r < 4; ++r) {
            float pp = p[r];
            pp += __shfl_xor(pp, 16);
            pp += __shfl_xor(pp, 32);
            int rw = cb + (r << 4);
            if (lane < 16) out[(rw << 6) + i] = fmaxf(pp + bb, 0.f);
        }
    }
}

extern "C" void kernel_launch(void* const* d_in, const int* in_sizes, int n_in,
                              void* d_out, int out_size, void* d_ws, size_t ws_size,
                              hipStream_t stream) {
    (void)in_sizes; (void)n_in; (void)out_size; (void)ws_size;
    const float* x   = (const float*)d_in[0];
    const float* W1a = (const float*)d_in[1];
    const float* W1b = (const float*)d_in[2];
    const float* W2a = (const float*)d_in[3];
    const float* W2b = (const float*)d_in[4];
    const float* W3a = (const float*)d_in[5];
    const float* b3a = (const float*)d_in[6];
    const float* W3b = (const float*)d_in[7];
    const float* b3b = (const float*)d_in[8];
    float* out = (float*)d_out;
    unsigned short* xb = (unsigned short*)d_ws;

    prep_x<<<512, 256, 0, stream>>>(x, xb);
    main_kernel<<<512, 256, 0, stream>>>(x, W1a, W1b, W2a, W2b, W3a, b3a, W3b, b3b, xb, out);
}

// Round 16
// 118.702 us; speedup vs baseline: 1.0118x; 1.0118x over previous
//
#include <hip/hip_runtime.h>

// N=64 nodes, H=64, M=32, B=16384.
// R11 base (51.3us, VERIFIED): LDS weight frags, 4-subtile chunks, cvt_pk.
// R13 failed absmax=inf with TWO bundled changes. R15 = controlled split:
// R11 + transposed-store ONLY (pkmax0 relu-fusion fully reverted).
// Store theory (measured): WRITE_SIZE 32MB vs 4MB logical = 8x amplification
// -- out[row][i] lines are partially written by 16 different blocks across
// XCDs. Fix: main writes ot[i][row] (16 lanes x 4B contiguous = 1 line),
// then untranspose kernel (padded-LDS 64x64 tile) emits out[row][i] fully
// coalesced. Guarded on ws_size >= 6MB with R11-identical fallback.

typedef short bf16x8 __attribute__((ext_vector_type(8)));
typedef float f32x4  __attribute__((ext_vector_type(4)));
typedef unsigned int u32x4 __attribute__((ext_vector_type(4)));

__device__ __forceinline__ unsigned int pack2(float a, float b) {
    // f32x2 -> packed bf16x2 in ONE VALU op (RTNE); a -> low16, b -> high16
    unsigned int r;
    asm("v_cvt_pk_bf16_f32 %0, %1, %2" : "=v"(r) : "v"(a), "v"(b));
    return r;
}

__device__ __forceinline__ f32x4 mfma16(bf16x8 a, bf16x8 b, f32x4 c) {
    return __builtin_amdgcn_mfma_f32_16x16x32_bf16(a, b, c, 0, 0, 0);
}

// pack two relu'd f32x4 D-blocks into one bf16x8 B-operand fragment
// (R11-proven form: fmaxf before cvt_pk)
__device__ __forceinline__ bf16x8 pack_frag(f32x4 lo, f32x4 hi) {
    union { u32x4 u; bf16x8 v; } r;
    r.u[0] = pack2(fmaxf(lo[0], 0.f), fmaxf(lo[1], 0.f));
    r.u[1] = pack2(fmaxf(lo[2], 0.f), fmaxf(lo[3], 0.f));
    r.u[2] = pack2(fmaxf(hi[0], 0.f), fmaxf(hi[1], 0.f));
    r.u[3] = pack2(fmaxf(hi[2], 0.f), fmaxf(hi[3], 0.f));
    return r.v;
}

// convert 2x f32x4 (possibly non-adjacent) into a bf16x8 A-fragment
__device__ __forceinline__ bf16x8 cvt_frag2(const float* __restrict__ plo,
                                            const float* __restrict__ phi) {
    f32x4 f0 = *(const f32x4*)plo;
    f32x4 f1 = *(const f32x4*)phi;
    union { u32x4 u; bf16x8 v; } r;
    r.u[0] = pack2(f0[0], f0[1]);
    r.u[1] = pack2(f0[2], f0[3]);
    r.u[2] = pack2(f1[0], f1[1]);
    r.u[3] = pack2(f1[2], f1[3]);
    return r.v;
}

__device__ __forceinline__ bf16x8 cvt_frag2_m(const float* __restrict__ plo,
                                              const float* __restrict__ phi,
                                              const unsigned int* M) {
    f32x4 f0 = *(const f32x4*)plo;
    f32x4 f1 = *(const f32x4*)phi;
    union { u32x4 u; bf16x8 v; } r;
    r.u[0] = pack2(f0[0], f0[1]) & M[0];
    r.u[1] = pack2(f0[2], f0[3]) & M[1];
    r.u[2] = pack2(f1[0], f1[1]) & M[2];
    r.u[3] = pack2(f1[2], f1[3]) & M[3];
    return r.v;
}

__global__ __launch_bounds__(256) void prep_x(const float* __restrict__ x,
                                              unsigned short* __restrict__ xb) {
    int j = (blockIdx.x * 256 + threadIdx.x) * 8;
    f32x4 a = *(const f32x4*)&x[j];
    f32x4 b = *(const f32x4*)&x[j + 4];
    u32x4 r = { pack2(a[0], a[1]), pack2(a[2], a[3]), pack2(b[0], b[1]), pack2(b[2], b[3]) };
    *(u32x4*)&xb[j] = r;
}

// out[row][i] = ot[i][row]; 64x64 tiles via padded LDS; coalesced both sides.
__global__ __launch_bounds__(256) void untranspose(const float* __restrict__ ot,
                                                   float* __restrict__ out) {
    __shared__ float t[64][65];
    const int b0 = blockIdx.x << 6;
    const int tid = threadIdx.x;
    #pragma unroll
    for (int s = 0; s < 16; ++s) {
        int idx = (s << 8) + tid;
        int il = idx >> 6, rl = idx & 63;
        t[il][rl] = ot[(il << 14) + b0 + rl];
    }
    __syncthreads();
    #pragma unroll
    for (int s = 0; s < 16; ++s) {
        int idx = (s << 8) + tid;
        int rl = idx >> 6, il = idx & 63;
        out[((b0 + rl) << 6) + il] = t[il][rl];
    }
}

__global__ __launch_bounds__(256, 2) void main_kernel(
    const float* __restrict__ x,
    const float* __restrict__ W1a, const float* __restrict__ W1b,
    const float* __restrict__ W2a, const float* __restrict__ W2b,
    const float* __restrict__ W3a, const float* __restrict__ b3a,
    const float* __restrict__ W3b, const float* __restrict__ b3b,
    const unsigned short* __restrict__ xb,
    float* __restrict__ ot, int staged,
    float* __restrict__ out)
{
    const int i    = blockIdx.x & 63;   // same-i blocks 64-strided -> same XCD (weight L2 locality)
    const int bg   = blockIdx.x >> 6;   // 0..7
    const int tid  = threadIdx.x;
    const int w    = tid >> 6;
    const int lane = tid & 63;
    const int q    = lane >> 4;
    const int c0   = lane & 15;

    // Layout: [0, 32768)B frag region (32 frags x 1024B);
    //         [32768, 33536)B s_vec region (3 x 256B);
    //         pad to 56320B -> 2 blocks/CU.
    __shared__ short lds[28160];

    // masks zeroing weight input-column i of W1a/W2a (== masking x column i)
    unsigned int M[2][4];
    {
        const unsigned int halfmask = (i & 1) ? 0x0000FFFFu : 0xFFFF0000u;
        const int dz = (i >> 1) & 3;
        #pragma unroll
        for (int s = 0; s < 2; ++s) {
            bool hit = ((i >> 3) == s * 4 + q);
            #pragma unroll
            for (int d = 0; d < 4; ++d)
                M[s][d] = (hit && d == dz) ? halfmask : 0xFFFFFFFFu;
        }
    }

    // ---- prologue: build all fragments in LDS (each wave owns 8 frag slots) ----
    if (w == 0) {
        const float* p1 = W1a + (i << 12);
        #pragma unroll
        for (int j = 0; j < 8; ++j) {
            int t = j >> 1, s = j & 1;
            int off = (((t << 4) + c0) << 6) + (s << 5) + (q << 3);
            bf16x8 fr = cvt_frag2_m(p1 + off, p1 + off + 4, M[s]);
            *(bf16x8*)&lds[j * 512 + lane * 8] = fr;
        }
    } else if (w == 1) {
        const float* p2 = W2a + (i << 12);
        #pragma unroll
        for (int j = 0; j < 8; ++j) {
            int t = j >> 1, s = j & 1;
            int off = (((t << 4) + c0) << 6) + (s << 5) + (q << 3);
            bf16x8 fr = cvt_frag2_m(p2 + off, p2 + off + 4, M[s]);
            *(bf16x8*)&lds[(8 + j) * 512 + lane * 8] = fr;
        }
    } else if (w == 2) {
        const float* p3 = W3a + (i << 13);
        #pragma unroll
        for (int j = 0; j < 8; ++j) {
            int t = j >> 1, s = j & 1;
            int base = (((t << 4) + c0) << 7) + (s << 5) + (q << 2);
            bf16x8 fr = cvt_frag2(p3 + base, p3 + base + 16);
            *(bf16x8*)&lds[(16 + j) * 512 + lane * 8] = fr;
        }
    } else {
        const float* pb1 = W1b + (i << 11);
        const float* pb2 = W2b + (i << 11);
        #pragma unroll
        for (int j = 0; j < 4; ++j) {
            int t = j >> 1, s = j & 1;
            int base = (((t << 4) + c0) << 6) + (s << 5) + (q << 2);
            bf16x8 fr1 = cvt_frag2(pb1 + base, pb1 + base + 16);
            bf16x8 fr2 = cvt_frag2(pb2 + base, pb2 + base + 16);
            *(bf16x8*)&lds[(24 + j) * 512 + lane * 8] = fr1;
            *(bf16x8*)&lds[(28 + j) * 512 + lane * 8] = fr2;
        }
    }
    if (tid < 64) {
        float* sv = (float*)&lds[16384];
        int tt = tid >> 4, qq = (tid >> 2) & 3, rr = tid & 3;
        sv[0 * 64 + tt * 16 + qq * 4 + rr] = b3a[(i << 6) + tid];
        sv[2 * 64 + tt * 16 + qq * 4 + rr] = W3b[(i << 6) + tid];
        sv[1 * 64 + tt * 16 + qq * 4 + rr] = W3a[(i << 13) + (tid << 7) + 64 + i];
    }
    const float bb = b3b[i];
    __syncthreads();

    const float* sv = (const float*)&lds[16384];

    const int wbase = (((bg << 2) + w) << 9);  // 512 rows per wave, 8 chunks of 64

    for (int k = 0; k < 8; ++k) {
        const int cb = wbase + (k << 6) + c0;

        // ---- load this chunk's 4 subtiles of x ----
        bf16x8 XB0[4], XB1[4]; float xd[4];
        #pragma unroll
        for (int r = 0; r < 4; ++r) {
            int rw = cb + (r << 4);
            XB0[r] = *(const bf16x8*)&xb[(rw << 6) + (q << 3)];
            XB1[r] = *(const bf16x8*)&xb[(rw << 6) + 32 + (q << 3)];
            xd[r]  = x[(rw << 6) + i];
        }

        // ---- phase A: x -> Ha (W1a), x -> Hb (W2a); 4 independent streams ----
        f32x4 a1[4][4], a2[4][4];
        #pragma unroll
        for (int t = 0; t < 4; ++t) {
            bf16x8 f10 = *(const bf16x8*)&lds[(t * 2 + 0) * 512 + lane * 8];
            bf16x8 f11 = *(const bf16x8*)&lds[(t * 2 + 1) * 512 + lane * 8];
            bf16x8 f20 = *(const bf16x8*)&lds[(8 + t * 2 + 0) * 512 + lane * 8];
            bf16x8 f21 = *(const bf16x8*)&lds[(8 + t * 2 + 1) * 512 + lane * 8];
            #pragma unroll
            for (int r = 0; r < 4; ++r) {
                f32x4 z = {0.f, 0.f, 0.f, 0.f};
                a1[t][r] = mfma16(f11, XB1[r], mfma16(f10, XB0[r], z));
                a2[t][r] = mfma16(f21, XB1[r], mfma16(f20, XB0[r], z));
            }
        }
        bf16x8 HB0[4], HB1[4], GB0[4], GB1[4];
        #pragma unroll
        for (int r = 0; r < 4; ++r) {
            HB0[r] = pack_frag(a1[0][r], a1[1][r]);
            HB1[r] = pack_frag(a1[2][r], a1[3][r]);
            GB0[r] = pack_frag(a2[0][r], a2[1][r]);
            GB1[r] = pack_frag(a2[2][r], a2[3][r]);
        }

        // ---- phase B: Ha -> r1 (W1b), Hb -> r2 (W2b) ----
        f32x4 b1[2][4], b2[2][4];
        #pragma unroll
        for (int t = 0; t < 2; ++t) {
            bf16x8 g10 = *(const bf16x8*)&lds[(24 + t * 2 + 0) * 512 + lane * 8];
            bf16x8 g11 = *(const bf16x8*)&lds[(24 + t * 2 + 1) * 512 + lane * 8];
            bf16x8 g20 = *(const bf16x8*)&lds[(28 + t * 2 + 0) * 512 + lane * 8];
            bf16x8 g21 = *(const bf16x8*)&lds[(28 + t * 2 + 1) * 512 + lane * 8];
            #pragma unroll
            for (int r = 0; r < 4; ++r) {
                f32x4 z = {0.f, 0.f, 0.f, 0.f};
                b1[t][r] = mfma16(g11, HB1[r], mfma16(g10, HB0[r], z));
                b2[t][r] = mfma16(g21, GB1[r], mfma16(g20, GB0[r], z));
            }
        }
        bf16x8 RB0[4], RB1[4];
        #pragma unroll
        for (int r = 0; r < 4; ++r) {
            RB0[r] = pack_frag(b1[0][r], b1[1][r]);   // r1 -> A3 s=0 slots
            RB1[r] = pack_frag(b2[0][r], b2[1][r]);   // r2 -> A3 s=1 slots
        }

        // ---- phase C: h = W3a'*[r1;r2] + xd*w3x + b3a; out = relu(dot(relu(h), w3b) + bb) ----
        float p[4] = {0.f, 0.f, 0.f, 0.f};
        #pragma unroll
        for (int t = 0; t < 4; ++t) {
            bf16x8 h0 = *(const bf16x8*)&lds[(16 + t * 2 + 0) * 512 + lane * 8];
            bf16x8 h1 = *(const bf16x8*)&lds[(16 + t * 2 + 1) * 512 + lane * 8];
            f32x4 bv = *(const f32x4*)&sv[0 * 64 + t * 16 + q * 4];
            f32x4 xv = *(const f32x4*)&sv[1 * 64 + t * 16 + q * 4];
            f32x4 wv = *(const f32x4*)&sv[2 * 64 + t * 16 + q * 4];
            #pragma unroll
            for (int r = 0; r < 4; ++r) {
                f32x4 acc;
                #pragma unroll
                for (int e = 0; e < 4; ++e) acc[e] = fmaf(xd[r], xv[e], bv[e]);
                acc = mfma16(h0, RB0[r], acc);
                acc = mfma16(h1, RB1[r], acc);
                #pragma unroll
                for (int e = 0; e < 4; ++e) p[r] = fmaf(fmaxf(acc[e], 0.f), wv[e], p[r]);
            }
        }
        #pragma unroll
        for (int r = 0; r < 4; ++r) {
            float pp = p[r];
            pp += __shfl_xor(pp, 16);
            pp += __shfl_xor(pp, 32);
            int rw = cb + (r << 4);
            if (lane < 16) {
                float v = fmaxf(pp + bb, 0.f);
                if (staged) ot[(i << 14) + rw] = v;      // [i][row]: 16x4B contiguous
                else        out[(rw << 6) + i] = v;      // R11-identical fallback
            }
        }
    }
}

extern "C" void kernel_launch(void* const* d_in, const int* in_sizes, int n_in,
                              void* d_out, int out_size, void* d_ws, size_t ws_size,
                              hipStream_t stream) {
    (void)in_sizes; (void)n_in; (void)out_size;
    const float* x   = (const float*)d_in[0];
    const float* W1a = (const float*)d_in[1];
    const float* W1b = (const float*)d_in[2];
    const float* W2a = (const float*)d_in[3];
    const float* W2b = (const float*)d_in[4];
    const float* W3a = (const float*)d_in[5];
    const float* b3a = (const float*)d_in[6];
    const float* W3b = (const float*)d_in[7];
    const float* b3b = (const float*)d_in[8];
    float* out = (float*)d_out;
    unsigned short* xb = (unsigned short*)d_ws;

    const int staged = (ws_size >= (size_t)(6u << 20)) ? 1 : 0;
    float* ot = (float*)((char*)d_ws + (2u << 20));

    prep_x<<<512, 256, 0, stream>>>(x, xb);
    main_kernel<<<512, 256, 0, stream>>>(x, W1a, W1b, W2a, W2b, W3a, b3a, W3b, b3b,
                                         xb, ot, staged, out);
    if (staged) untranspose<<<256, 256, 0, stream>>>(ot, out);
}

// Round 19
// 114.560 us; speedup vs baseline: 1.0484x; 1.0362x over previous
//
#include <hip/hip_runtime.h>

// N=64 nodes, H=64, M=32, B=16384.
// FINAL (R18): byte-for-byte resubmission of R11, the best verified kernel
// (dur_us 114.8; main_kernel 51.3us; absmax 9.8e-4). Session summary:
//  - R4: weights -> LDS bf16 MFMA fragments once per block (68 -> 59us)
//  - R8: v_cvt_pk_bf16_f32 pack, 1 VALU/pair (59 -> 55.4us)
//  - R9: LDS pad -> 2 blocks/CU budget (55.4 -> 53us)
//  - R11: 4-subtile chunks, 4 independent MFMA streams (53 -> 51.3us)
// Dead ends (all counter-verified): register pinning (scheduler always
// sinks remat-able loads; R1-R3/R9/R10), launch_bounds>=3 (spill cascade,
// R5/R6), grid occupancy (2 blocks/CU dispatcher cap, R7), SGB schedule
// pinning (regressed, R12), store de-amplification (WRITE 32->4MB but
// time-neutral, R15), 512-thread blocks (absmax=inf twice, R16/R17).
// Remaining gap is ~54% dependency stall on the serial A->pack->B->pack->C
// chain at 2 waves/SIMD with compiler-enforced ~100-VGPR schedules --
// structural for this kernel shape in plain HIP on this stack.

typedef short bf16x8 __attribute__((ext_vector_type(8)));
typedef float f32x4  __attribute__((ext_vector_type(4)));
typedef unsigned int u32x4 __attribute__((ext_vector_type(4)));

__device__ __forceinline__ unsigned int pack2(float a, float b) {
    // f32x2 -> packed bf16x2 in ONE VALU op (RTNE); a -> low16, b -> high16
    unsigned int r;
    asm("v_cvt_pk_bf16_f32 %0, %1, %2" : "=v"(r) : "v"(a), "v"(b));
    return r;
}

__device__ __forceinline__ f32x4 mfma16(bf16x8 a, bf16x8 b, f32x4 c) {
    return __builtin_amdgcn_mfma_f32_16x16x32_bf16(a, b, c, 0, 0, 0);
}

// pack two relu'd f32x4 D-blocks into one bf16x8 B-operand fragment
__device__ __forceinline__ bf16x8 pack_frag(f32x4 lo, f32x4 hi) {
    union { u32x4 u; bf16x8 v; } r;
    r.u[0] = pack2(fmaxf(lo[0], 0.f), fmaxf(lo[1], 0.f));
    r.u[1] = pack2(fmaxf(lo[2], 0.f), fmaxf(lo[3], 0.f));
    r.u[2] = pack2(fmaxf(hi[0], 0.f), fmaxf(hi[1], 0.f));
    r.u[3] = pack2(fmaxf(hi[2], 0.f), fmaxf(hi[3], 0.f));
    return r.v;
}

// convert 2x f32x4 (possibly non-adjacent) into a bf16x8 A-fragment
__device__ __forceinline__ bf16x8 cvt_frag2(const float* __restrict__ plo,
                                            const float* __restrict__ phi) {
    f32x4 f0 = *(const f32x4*)plo;
    f32x4 f1 = *(const f32x4*)phi;
    union { u32x4 u; bf16x8 v; } r;
    r.u[0] = pack2(f0[0], f0[1]);
    r.u[1] = pack2(f0[2], f0[3]);
    r.u[2] = pack2(f1[0], f1[1]);
    r.u[3] = pack2(f1[2], f1[3]);
    return r.v;
}

__device__ __forceinline__ bf16x8 cvt_frag2_m(const float* __restrict__ plo,
                                              const float* __restrict__ phi,
                                              const unsigned int* M) {
    f32x4 f0 = *(const f32x4*)plo;
    f32x4 f1 = *(const f32x4*)phi;
    union { u32x4 u; bf16x8 v; } r;
    r.u[0] = pack2(f0[0], f0[1]) & M[0];
    r.u[1] = pack2(f0[2], f0[3]) & M[1];
    r.u[2] = pack2(f1[0], f1[1]) & M[2];
    r.u[3] = pack2(f1[2], f1[3]) & M[3];
    return r.v;
}

__global__ __launch_bounds__(256) void prep_x(const float* __restrict__ x,
                                              unsigned short* __restrict__ xb) {
    int j = (blockIdx.x * 256 + threadIdx.x) * 8;
    f32x4 a = *(const f32x4*)&x[j];
    f32x4 b = *(const f32x4*)&x[j + 4];
    u32x4 r = { pack2(a[0], a[1]), pack2(a[2], a[3]), pack2(b[0], b[1]), pack2(b[2], b[3]) };
    *(u32x4*)&xb[j] = r;
}

__global__ __launch_bounds__(256, 2) void main_kernel(
    const float* __restrict__ x,
    const float* __restrict__ W1a, const float* __restrict__ W1b,
    const float* __restrict__ W2a, const float* __restrict__ W2b,
    const float* __restrict__ W3a, const float* __restrict__ b3a,
    const float* __restrict__ W3b, const float* __restrict__ b3b,
    const unsigned short* __restrict__ xb,
    float* __restrict__ out)
{
    const int i    = blockIdx.x & 63;   // same-i blocks 64-strided -> same XCD (weight L2 locality)
    const int bg   = blockIdx.x >> 6;   // 0..7
    const int tid  = threadIdx.x;
    const int w    = tid >> 6;
    const int lane = tid & 63;
    const int q    = lane >> 4;
    const int c0   = lane & 15;

    // Layout: [0, 32768)B frag region (32 frags x 1024B);
    //         [32768, 33536)B s_vec region (3 x 256B);
    //         pad to 56320B -> 2 blocks/CU.
    __shared__ short lds[28160];

    // masks zeroing weight input-column i of W1a/W2a (== masking x column i)
    unsigned int M[2][4];
    {
        const unsigned int halfmask = (i & 1) ? 0x0000FFFFu : 0xFFFF0000u;
        const int dz = (i >> 1) & 3;
        #pragma unroll
        for (int s = 0; s < 2; ++s) {
            bool hit = ((i >> 3) == s * 4 + q);
            #pragma unroll
            for (int d = 0; d < 4; ++d)
                M[s][d] = (hit && d == dz) ? halfmask : 0xFFFFFFFFu;
        }
    }

    // ---- prologue: build all fragments in LDS (each wave owns 8 frag slots) ----
    if (w == 0) {
        const float* p1 = W1a + (i << 12);
        #pragma unroll
        for (int j = 0; j < 8; ++j) {
            int t = j >> 1, s = j & 1;
            int off = (((t << 4) + c0) << 6) + (s << 5) + (q << 3);
            bf16x8 fr = cvt_frag2_m(p1 + off, p1 + off + 4, M[s]);
            *(bf16x8*)&lds[j * 512 + lane * 8] = fr;
        }
    } else if (w == 1) {
        const float* p2 = W2a + (i << 12);
        #pragma unroll
        for (int j = 0; j < 8; ++j) {
            int t = j >> 1, s = j & 1;
            int off = (((t << 4) + c0) << 6) + (s << 5) + (q << 3);
            bf16x8 fr = cvt_frag2_m(p2 + off, p2 + off + 4, M[s]);
            *(bf16x8*)&lds[(8 + j) * 512 + lane * 8] = fr;
        }
    } else if (w == 2) {
        const float* p3 = W3a + (i << 13);
        #pragma unroll
        for (int j = 0; j < 8; ++j) {
            int t = j >> 1, s = j & 1;
            int base = (((t << 4) + c0) << 7) + (s << 5) + (q << 2);
            bf16x8 fr = cvt_frag2(p3 + base, p3 + base + 16);
            *(bf16x8*)&lds[(16 + j) * 512 + lane * 8] = fr;
        }
    } else {
        const float* pb1 = W1b + (i << 11);
        const float* pb2 = W2b + (i << 11);
        #pragma unroll
        for (int j = 0; j < 4; ++j) {
            int t = j >> 1, s = j & 1;
            int base = (((t << 4) + c0) << 6) + (s << 5) + (q << 2);
            bf16x8 fr1 = cvt_frag2(pb1 + base, pb1 + base + 16);
            bf16x8 fr2 = cvt_frag2(pb2 + base, pb2 + base + 16);
            *(bf16x8*)&lds[(24 + j) * 512 + lane * 8] = fr1;
            *(bf16x8*)&lds[(28 + j) * 512 + lane * 8] = fr2;
        }
    }
    if (tid < 64) {
        float* sv = (float*)&lds[16384];
        int tt = tid >> 4, qq = (tid >> 2) & 3, rr = tid & 3;
        sv[0 * 64 + tt * 16 + qq * 4 + rr] = b3a[(i << 6) + tid];
        sv[2 * 64 + tt * 16 + qq * 4 + rr] = W3b[(i << 6) + tid];
        sv[1 * 64 + tt * 16 + qq * 4 + rr] = W3a[(i << 13) + (tid << 7) + 64 + i];
    }
    const float bb = b3b[i];
    __syncthreads();

    const float* sv = (const float*)&lds[16384];

    const int wbase = (((bg << 2) + w) << 9);  // 512 rows per wave, 8 chunks of 64

    for (int k = 0; k < 8; ++k) {
        const int cb = wbase + (k << 6) + c0;

        // ---- load this chunk's 4 subtiles of x ----
        bf16x8 XB0[4], XB1[4]; float xd[4];
        #pragma unroll
        for (int r = 0; r < 4; ++r) {
            int rw = cb + (r << 4);
            XB0[r] = *(const bf16x8*)&xb[(rw << 6) + (q << 3)];
            XB1[r] = *(const bf16x8*)&xb[(rw << 6) + 32 + (q << 3)];
            xd[r]  = x[(rw << 6) + i];
        }

        // ---- phase A: x -> Ha (W1a), x -> Hb (W2a); 4 independent streams ----
        f32x4 a1[4][4], a2[4][4];
        #pragma unroll
        for (int t = 0; t < 4; ++t) {
            bf16x8 f10 = *(const bf16x8*)&lds[(t * 2 + 0) * 512 + lane * 8];
            bf16x8 f11 = *(const bf16x8*)&lds[(t * 2 + 1) * 512 + lane * 8];
            bf16x8 f20 = *(const bf16x8*)&lds[(8 + t * 2 + 0) * 512 + lane * 8];
            bf16x8 f21 = *(const bf16x8*)&lds[(8 + t * 2 + 1) * 512 + lane * 8];
            #pragma unroll
            for (int r = 0; r < 4; ++r) {
                f32x4 z = {0.f, 0.f, 0.f, 0.f};
                a1[t][r] = mfma16(f11, XB1[r], mfma16(f10, XB0[r], z));
                a2[t][r] = mfma16(f21, XB1[r], mfma16(f20, XB0[r], z));
            }
        }
        bf16x8 HB0[4], HB1[4], GB0[4], GB1[4];
        #pragma unroll
        for (int r = 0; r < 4; ++r) {
            HB0[r] = pack_frag(a1[0][r], a1[1][r]);
            HB1[r] = pack_frag(a1[2][r], a1[3][r]);
            GB0[r] = pack_frag(a2[0][r], a2[1][r]);
            GB1[r] = pack_frag(a2[2][r], a2[3][r]);
        }

        // ---- phase B: Ha -> r1 (W1b), Hb -> r2 (W2b) ----
        f32x4 b1[2][4], b2[2][4];
        #pragma unroll
        for (int t = 0; t < 2; ++t) {
            bf16x8 g10 = *(const bf16x8*)&lds[(24 + t * 2 + 0) * 512 + lane * 8];
            bf16x8 g11 = *(const bf16x8*)&lds[(24 + t * 2 + 1) * 512 + lane * 8];
            bf16x8 g20 = *(const bf16x8*)&lds[(28 + t * 2 + 0) * 512 + lane * 8];
            bf16x8 g21 = *(const bf16x8*)&lds[(28 + t * 2 + 1) * 512 + lane * 8];
            #pragma unroll
            for (int r = 0; r < 4; ++r) {
                f32x4 z = {0.f, 0.f, 0.f, 0.f};
                b1[t][r] = mfma16(g11, HB1[r], mfma16(g10, HB0[r], z));
                b2[t][r] = mfma16(g21, GB1[r], mfma16(g20, GB0[r], z));
            }
        }
        bf16x8 RB0[4], RB1[4];
        #pragma unroll
        for (int r = 0; r < 4; ++r) {
            RB0[r] = pack_frag(b1[0][r], b1[1][r]);   // r1 -> A3 s=0 slots
            RB1[r] = pack_frag(b2[0][r], b2[1][r]);   // r2 -> A3 s=1 slots
        }

        // ---- phase C: h = W3a'*[r1;r2] + xd*w3x + b3a; out = relu(dot(relu(h), w3b) + bb) ----
        float p[4] = {0.f, 0.f, 0.f, 0.f};
        #pragma unroll
        for (int t = 0; t < 4; ++t) {
            bf16x8 h0 = *(const bf16x8*)&lds[(16 + t * 2 + 0) * 512 + lane * 8];
            bf16x8 h1 = *(const bf16x8*)&lds[(16 + t * 2 + 1) * 512 + lane * 8];
            f32x4 bv = *(const f32x4*)&sv[0 * 64 + t * 16 + q * 4];
            f32x4 xv = *(const f32x4*)&sv[1 * 64 + t * 16 + q * 4];
            f32x4 wv = *(const f32x4*)&sv[2 * 64 + t * 16 + q * 4];
            #pragma unroll
            for (int r = 0; r < 4; ++r) {
                f32x4 acc;
                #pragma unroll
                for (int e = 0; e < 4; ++e) acc[e] = fmaf(xd[r], xv[e], bv[e]);
                acc = mfma16(h0, RB0[r], acc);
                acc = mfma16(h1, RB1[r], acc);
                #pragma unroll
                for (int e = 0; e < 4; ++e) p[r] = fmaf(fmaxf(acc[e], 0.f), wv[e], p[r]);
            }
        }
        #pragma unroll
        for (int r = 0; r < 4; ++r) {
            float pp = p[r];
            pp += __shfl_xor(pp, 16);
            pp += __shfl_xor(pp, 32);
            int rw = cb + (r << 4);
            if (lane < 16) out[(rw << 6) + i] = fmaxf(pp + bb, 0.f);
        }
    }
}

extern "C" void kernel_launch(void* const* d_in, const int* in_sizes, int n_in,
                              void* d_out, int out_size, void* d_ws, size_t ws_size,
                              hipStream_t stream) {
    (void)in_sizes; (void)n_in; (void)out_size; (void)ws_size;
    const float* x   = (const float*)d_in[0];
    const float* W1a = (const float*)d_in[1];
    const float* W1b = (const float*)d_in[2];
    const float* W2a = (const float*)d_in[3];
    const float* W2b = (const float*)d_in[4];
    const float* W3a = (const float*)d_in[5];
    const float* b3a = (const float*)d_in[6];
    const float* W3b = (const float*)d_in[7];
    const float* b3b = (const float*)d_in[8];
    float* out = (float*)d_out;
    unsigned short* xb = (unsigned short*)d_ws;

    prep_x<<<512, 256, 0, stream>>>(x, xb);
    main_kernel<<<512, 256, 0, stream>>>(x, W1a, W1b, W2a, W2b, W3a, b3a, W3b, b3b, xb, out);
}